// Round 1
// baseline (196.125 us; speedup 1.0000x reference)
//
#include <hip/hip_runtime.h>
#include <hip/hip_bf16.h>

// FlippedQuanv3x3 == 3x3 conv (C=16 -> O=64, pad=1) with transformed weight
// Weff[o,c,k9] = 0.25*(sum_i w[o,c,i]*A[i,k9] + t0[k9]).
// Implicit GEMM, bf16 MFMA 16x16x32. K order = tap-major: k = tap*16 + c.
// K = 144 padded to 160 = 5 chunks. A = im2col(x) (M = pixels), B = Weff (N = o).
//
// R4 change (theory: HBM write-page thrash): the old direct store path wrote
// 16 x 64B chunks at 64-KiB stride per instruction, advancing each (o,row)
// stream 128 B per ~400 cycles -> ~131K concurrent write streams >> HBM banks
// -> page-miss on nearly every write (~2.4 TB/s effective, conv ~68 us vs
// ~28 us traffic roofline). Now: hold full-row accumulators (128 VGPR),
// bounce through a wave-private 8-KiB LDS slice, and emit contiguous
// 1-KiB-per-instruction non-temporal stores (each o-plane row = 1 instr,
// planes back-to-back). No extra barriers (wave-private buffer).

typedef short bf16x8 __attribute__((ext_vector_type(8)));   // 8 bf16 = 4 VGPR
typedef float f32x4 __attribute__((ext_vector_type(4)));

// ---- Pauli feature constants (verified R1-R3) ----
__device__ __forceinline__ void pauli_entry(int s, int r, int c, float& re, float& im) {
    re = 0.f; im = 0.f;
    if (s == 0)      { if (r == c) re = 1.f; }
    else if (s == 1) { if (r != c) re = 1.f; }
    else if (s == 2) { if (r == 0 && c == 1) im = -1.f; else if (r == 1 && c == 0) im = 1.f; }
    else             { if (r == c) re = (r == 0) ? 1.f : -1.f; }
}

__device__ __forceinline__ float A_entry(int i, int k) {
    int j = i + 1, sa = j >> 2, sb = j & 3;
    int r = k >> 2, c = k & 3;        // 4x4 flat embedding (M.flat[k]) — verified R1
    float ar, ai, br, bi;
    pauli_entry(sa, r >> 1, c >> 1, ar, ai);
    pauli_entry(sb, r & 1, c & 1, br, bi);
    float re1 = ar * br - ai * bi;
    pauli_entry(sa, c >> 1, r >> 1, ar, ai);
    pauli_entry(sb, c & 1, r & 1, br, bi);
    float re2 = ar * br - ai * bi;
    return 0.5f * (re1 + re2);
}

__device__ __forceinline__ short f2bf(float f) {   // RNE float->bf16 bits
    union { float f; unsigned int u; } a; a.f = f;
    unsigned int r = a.u + 0x7fffu + ((a.u >> 16) & 1u);
    return (short)(r >> 16);
}

// pack two floats -> two bf16 (RNE) in one u32 (lo = a, hi = b)
__device__ __forceinline__ unsigned pk_bf16(float a, float b) {
#if __has_builtin(__builtin_amdgcn_cvt_pk_bf16_f32)
    typedef __bf16 bf2 __attribute__((ext_vector_type(2)));
    bf2 r = __builtin_amdgcn_cvt_pk_bf16_f32(a, b);
    union { bf2 v; unsigned u; } cv; cv.v = r;
    return cv.u;
#else
    union { float f; unsigned u; } x, y; x.f = a; y.f = b;
    unsigned ra = x.u + 0x7fffu + ((x.u >> 16) & 1u);
    unsigned rb = y.u + 0x7fffu + ((y.u >> 16) & 1u);
    return (ra >> 16) | (rb & 0xffff0000u);
#endif
}

// ---- prep: Weff as MFMA B-fragments, k tap-major.
// bfrag[(chunk*4 + ot)*64 + lane][j] = Weff[o = ot*16 + (lane&15)]
//   [gk = chunk*32 + (lane>>4)*8 + j], gk -> (tap = gk>>4, c = gk&15); 0 if gk>=144.
// R4: A-table built once in LDS (135 evals/block) instead of 120 branchy
// A_entry evals per thread -> prep VALU cut ~100x.
__global__ __launch_bounds__(256) void prep_kernel(const float* __restrict__ weight,
                                                   short* __restrict__ bfrag) {
    __shared__ float Ash[135];       // Ash[i*9 + tap] = A[i, tap]
    int tid = threadIdx.x;
    if (tid < 135) Ash[tid] = A_entry(tid / 9, tid % 9);
    __syncthreads();

    int t = blockIdx.x * 256 + tid;
    if (t >= 1280) return;
    int lane  = t & 63;
    int ot    = (t >> 6) & 3;
    int chunk = t >> 8;
    int q     = lane >> 4;
    int o     = ot * 16 + (lane & 15);
    short vals[8];
    #pragma unroll
    for (int j = 0; j < 8; ++j) {
        int gk = chunk * 32 + q * 8 + j;
        float v = 0.f;
        if (gk < 144) {
            int tap = gk >> 4;         // patch index 0..8
            int c   = gk & 15;         // channel
            float acc = (tap == 0 || tap == 5) ? 1.f : 0.f;   // t0
            const float* w = weight + (o * 16 + c) * 15;
            #pragma unroll
            for (int i = 0; i < 15; ++i) acc += w[i] * Ash[i * 9 + tap];
            v = 0.25f * acc;
        }
        vals[j] = f2bf(v);
    }
    *(bf16x8*)(bfrag + t * 8) = *(bf16x8*)vals;
}

// LDS x-tile element index: el(row, w, c) = (row*136 + w)*16 + slot*8 + (c&7),
// slot = (c>>3) ^ ((w>>2)&1). row in [0,10) = x rows h0-1..h0+8; w in [0,136)
// = x w -4..131. Row stride 4352 B == 0 mod 32 banks; the (w>>2) XOR keeps
// hot-loop b128 reads <=2-way conflicted (free, m136).
__global__ __launch_bounds__(256, 2) void conv_mfma(const float* __restrict__ x,
                                                    const short* __restrict__ bfrag,
                                                    const float* __restrict__ bias,
                                                    float* __restrict__ out) {
    __shared__ short sx[10 * 136 * 16];            // 43520 B
    __shared__ __align__(16) float obuf[8192];     // 32768 B epilogue bounce (8 KiB/wave)

    const int tid  = threadIdx.x;
    const int h0   = blockIdx.x * 8;
    const int b    = blockIdx.y;
    const int lane = tid & 63;
    const int wave = tid >> 6;
    const int q    = lane >> 4;
    const int nlo  = lane & 15;

    // ---- stage x -> bf16 c-fastest LDS tile. 2720 positions = (row,chalf,w).
    const float* xb = x + (size_t)b * 16 * 128 * 128;
    #pragma unroll
    for (int it = 0; it < 11; ++it) {
        int pos = tid + it * 256;
        if (pos < 2720) {
            int seg = pos / 136;           // row*2 + chalf
            int w   = pos - seg * 136;
            int row = seg >> 1, chalf = seg & 1;
            int hp  = h0 - 1 + row;
            int xw  = w - 4;
            bool ok = ((unsigned)hp < 128u) && ((unsigned)xw < 128u);
            const float* src = xb + (size_t)(chalf * 8) * 16384 + hp * 128 + xw;
            float v[8];
            #pragma unroll
            for (int j = 0; j < 8; ++j)
                v[j] = ok ? src[(size_t)j * 16384] : 0.f;
            int slot = (chalf ^ (w >> 2)) & 1;
            unsigned* dst = (unsigned*)sx + (row * 136 + w) * 8 + slot * 4;
            #pragma unroll
            for (int j2 = 0; j2 < 4; ++j2)
                dst[j2] = pk_bf16(v[2 * j2], v[2 * j2 + 1]);
        }
    }

    // ---- weights into registers (80 VGPR), bias per lane
    bf16x8 Breg[20];
    #pragma unroll
    for (int i = 0; i < 20; ++i)
        Breg[i] = *(const bf16x8*)(bfrag + (i * 64 + lane) * 8);
    float bv[4];
    #pragma unroll
    for (int ot = 0; ot < 4; ++ot) bv[ot] = bias[ot * 16 + nlo];

    // ---- per-chunk A-read base. Row ownership (R4): wave owns output row
    // h = h0 + rs*4 + wave, so each rs-phase covers 4 CONTIGUOUS rows.
    int baseA[5];
    #pragma unroll
    for (int ch = 0; ch < 5; ++ch) {
        int tap = ch * 2 + (q >> 1);
        if (tap > 8) tap = 8;             // chunk 4 upper half: pad, B=0
        int kh = tap / 3, kw = tap - 3 * kh;
        int chalf = q & 1;
        int row0  = wave + kh;            // rs adds 4 rows (rs*8704 elements)
        int w0    = nlo + kw + 3;         // LDS w-index for pixel nlo
        int slot  = (chalf ^ (w0 >> 2)) & 1;
        baseA[ch] = (row0 * 136 + w0) * 16 + slot * 8;
    }
    __syncthreads();

    // ---- hot loop: 2 rs-phases x (full-row accumulate, then LDS-bounced
    // contiguous epilogue). acc[np][ot][mt] = 128 VGPR held per phase.
    #pragma unroll
    for (int rs = 0; rs < 2; ++rs) {
        f32x4 acc[4][4][2];
        #pragma unroll
        for (int np = 0; np < 4; ++np)
            #pragma unroll
            for (int ot = 0; ot < 4; ++ot) {
                f32x4 ini = { bv[ot], bv[ot], bv[ot], bv[ot] };
                acc[np][ot][0] = ini;
                acc[np][ot][1] = ini;
            }
        #pragma unroll
        for (int np = 0; np < 4; ++np) {
            #pragma unroll
            for (int ch = 0; ch < 5; ++ch) {
                const short* pA = sx + baseA[ch] + rs * 8704 + np * 512;
                bf16x8 A0 = *(const bf16x8*)(pA);        // m-tile 0 (pixels +0)
                bf16x8 A1 = *(const bf16x8*)(pA + 256);  // m-tile 1 (pixels +16)
                #pragma unroll
                for (int ot = 0; ot < 4; ++ot) {
                    acc[np][ot][0] = __builtin_amdgcn_mfma_f32_16x16x32_bf16(A0, Breg[ch * 4 + ot], acc[np][ot][0], 0, 0, 0);
                    acc[np][ot][1] = __builtin_amdgcn_mfma_f32_16x16x32_bf16(A1, Breg[ch * 4 + ot], acc[np][ot][1], 0, 0, 0);
                }
            }
        }
        // ---- epilogue: per ot-group, wave-private LDS transpose then
        // contiguous non-temporal stores. D[m = q*4+reg (pixel), n = nlo (o)].
        // Write:  obuf[wave*2048 + o*128 + (w ^ ((o&7)<<2))]  (8 lanes/bank-group)
        // Read:   64 lanes x 16 B = 1 KiB contiguous per instruction; each
        //         o-plane's 512-B row leaves in ONE instruction, planes walked
        //         back-to-back -> DRAM-page-friendly write stream.
        #pragma unroll
        for (int ot = 0; ot < 4; ++ot) {
            #pragma unroll
            for (int np = 0; np < 4; ++np)
                #pragma unroll
                for (int mt = 0; mt < 2; ++mt) {
                    int wpart = np * 32 + mt * 16 + q * 4;
                    int widx  = wave * 2048 + nlo * 128 + (wpart ^ ((nlo & 7) << 2));
                    *(f32x4*)(obuf + widx) = acc[np][ot][mt];
                }
            // no barrier needed: obuf slice is wave-private; in-wave DS
            // ordering (lgkmcnt) covers write->read.
            float* outp = out + ((((size_t)b * 64 + ot * 16) * 128)
                                 + h0 + rs * 4 + wave) * 128;
            #pragma unroll
            for (int r = 0; r < 8; ++r) {
                int L  = r * 256 + lane * 4;       // per-wave region, 2048 floats
                int o  = (L >> 7) & 15;
                int wp = L & 127;
                int ridx = wave * 2048 + o * 128 + (wp ^ ((o & 7) << 2));
                f32x4 v = *(const f32x4*)(obuf + ridx);
                __builtin_nontemporal_store(v, (f32x4*)(outp + (size_t)o * 16384 + wp));
            }
        }
    }
}

extern "C" void kernel_launch(void* const* d_in, const int* in_sizes, int n_in,
                              void* d_out, int out_size, void* d_ws, size_t ws_size,
                              hipStream_t stream) {
    const float* x      = (const float*)d_in[0];   // [32,16,128,128]
    const float* weight = (const float*)d_in[1];   // [64,16,15]
    const float* bias   = (const float*)d_in[2];   // [64,1]
    float* out   = (float*)d_out;                  // [32,64,128,128]
    short* bfrag = (short*)d_ws;                   // 1280*8 bf16 = 20 KB

    prep_kernel<<<5, 256, 0, stream>>>(weight, bfrag);
    dim3 grid(16, 32);                             // (h-tiles of 8 rows, b)
    conv_mfma<<<grid, 256, 0, stream>>>(x, bfrag, bias, out);
}

// Round 2
// 190.759 us; speedup vs baseline: 1.0281x; 1.0281x over previous
//
#include <hip/hip_runtime.h>
#include <hip/hip_bf16.h>

// FlippedQuanv3x3 == 3x3 conv (C=16 -> O=64, pad=1) with transformed weight
// Weff[o,c,k9] = 0.25*(sum_i w[o,c,i]*A[i,k9] + t0[k9]).
// Implicit GEMM, bf16 MFMA 16x16x32. K order = tap-major: k = tap*16 + c
// (tap = 3x3 patch index 0..8, c = channel). K = 144 padded to 160 = 5 chunks.
// Operand roles: A = im2col(x) (M = pixels), B = Weff (N = o). Lane's A-frag
// (8 k = 8 consecutive c) = ONE ds_read_b128 from a c-fastest bf16 LDS tile.
// D rows = pixels -> each lane stores 4 consecutive pixels (dwordx4).
// Block = (b, 8 output rows); grid 16x32 = 512 = exactly 2 blocks/CU.
//
// R5: exact R0 structure (169 us proven); ONE conv change: epilogue stores are
// non-temporal. Theory: 16x64B chunks @64-KiB stride collapse onto few L2 sets
// shared by 32 CUs/XCD -> write-allocate line fetches + half-dirty evictions
// ~2-3x store cost. nt bypasses L2 write-allocate; HBM3E native granularity
// is 64 B, so 64-B nt chunks stream at full efficiency.
// (R4's bundled rewrite regressed +27 us -> diagnosed as VGPR spill confound.)

typedef short bf16x8 __attribute__((ext_vector_type(8)));   // 8 bf16 = 4 VGPR
typedef float f32x4 __attribute__((ext_vector_type(4)));

// ---- Pauli feature constants (verified R1-R3) ----
__device__ __forceinline__ void pauli_entry(int s, int r, int c, float& re, float& im) {
    re = 0.f; im = 0.f;
    if (s == 0)      { if (r == c) re = 1.f; }
    else if (s == 1) { if (r != c) re = 1.f; }
    else if (s == 2) { if (r == 0 && c == 1) im = -1.f; else if (r == 1 && c == 0) im = 1.f; }
    else             { if (r == c) re = (r == 0) ? 1.f : -1.f; }
}

__device__ __forceinline__ float A_entry(int i, int k) {
    int j = i + 1, sa = j >> 2, sb = j & 3;
    int r = k >> 2, c = k & 3;        // 4x4 flat embedding (M.flat[k]) — verified R1
    float ar, ai, br, bi;
    pauli_entry(sa, r >> 1, c >> 1, ar, ai);
    pauli_entry(sb, r & 1, c & 1, br, bi);
    float re1 = ar * br - ai * bi;
    pauli_entry(sa, c >> 1, r >> 1, ar, ai);
    pauli_entry(sb, c & 1, r & 1, br, bi);
    float re2 = ar * br - ai * bi;
    return 0.5f * (re1 + re2);
}

__device__ __forceinline__ short f2bf(float f) {   // RNE float->bf16 bits
    union { float f; unsigned int u; } a; a.f = f;
    unsigned int r = a.u + 0x7fffu + ((a.u >> 16) & 1u);
    return (short)(r >> 16);
}

// pack two floats -> two bf16 (RNE) in one u32 (lo = a, hi = b)
__device__ __forceinline__ unsigned pk_bf16(float a, float b) {
#if __has_builtin(__builtin_amdgcn_cvt_pk_bf16_f32)
    typedef __bf16 bf2 __attribute__((ext_vector_type(2)));
    bf2 r = __builtin_amdgcn_cvt_pk_bf16_f32(a, b);
    union { bf2 v; unsigned u; } cv; cv.v = r;
    return cv.u;
#else
    union { float f; unsigned u; } x, y; x.f = a; y.f = b;
    unsigned ra = x.u + 0x7fffu + ((x.u >> 16) & 1u);
    unsigned rb = y.u + 0x7fffu + ((y.u >> 16) & 1u);
    return (ra >> 16) | (rb & 0xffff0000u);
#endif
}

// ---- prep: Weff as MFMA B-fragments, k tap-major.
// bfrag[(chunk*4 + ot)*64 + lane][j] = Weff[o = ot*16 + (lane&15)]
//   [gk = chunk*32 + (lane>>4)*8 + j], gk -> (tap = gk>>4, c = gk&15); 0 if gk>=144.
// A-table built once in LDS (135 evals/block) instead of 120 branchy
// A_entry evals per thread.
__global__ __launch_bounds__(256) void prep_kernel(const float* __restrict__ weight,
                                                   short* __restrict__ bfrag) {
    __shared__ float Ash[135];       // Ash[i*9 + tap] = A[i, tap]
    int tid = threadIdx.x;
    if (tid < 135) Ash[tid] = A_entry(tid / 9, tid % 9);
    __syncthreads();

    int t = blockIdx.x * 256 + tid;
    if (t >= 1280) return;
    int lane  = t & 63;
    int ot    = (t >> 6) & 3;
    int chunk = t >> 8;
    int q     = lane >> 4;
    int o     = ot * 16 + (lane & 15);
    short vals[8];
    #pragma unroll
    for (int j = 0; j < 8; ++j) {
        int gk = chunk * 32 + q * 8 + j;
        float v = 0.f;
        if (gk < 144) {
            int tap = gk >> 4;         // patch index 0..8
            int c   = gk & 15;         // channel
            float acc = (tap == 0 || tap == 5) ? 1.f : 0.f;   // t0
            const float* w = weight + (o * 16 + c) * 15;
            #pragma unroll
            for (int i = 0; i < 15; ++i) acc += w[i] * Ash[i * 9 + tap];
            v = 0.25f * acc;
        }
        vals[j] = f2bf(v);
    }
    *(bf16x8*)(bfrag + t * 8) = *(bf16x8*)vals;
}

// LDS element index: el(row, w, c) = (row*136 + w)*16 + slot*8 + (c&7),
// slot = (c>>3) ^ ((w>>2)&1). row in [0,10) = x rows h0-1..h0+8; w in [0,136)
// = x w -4..131. 136*16 el/row => row stride 4352 B == 0 mod 32 banks; the
// (w>>2) XOR keeps hot-loop b128 reads <=2-way conflicted (free, m136).
__global__ __launch_bounds__(256) void conv_mfma(const float* __restrict__ x,
                                                 const short* __restrict__ bfrag,
                                                 const float* __restrict__ bias,
                                                 float* __restrict__ out) {
    __shared__ short sx[10 * 136 * 16];   // 43520 B

    const int tid  = threadIdx.x;
    const int h0   = blockIdx.x * 8;
    const int b    = blockIdx.y;
    const int lane = tid & 63;
    const int wave = tid >> 6;
    const int q    = lane >> 4;
    const int nlo  = lane & 15;

    // ---- stage x -> bf16 c-fastest LDS tile. 2720 positions = (row,chalf,w).
    const float* xb = x + (size_t)b * 16 * 128 * 128;
    #pragma unroll
    for (int it = 0; it < 11; ++it) {
        int pos = tid + it * 256;
        if (pos < 2720) {
            int seg = pos / 136;           // row*2 + chalf
            int w   = pos - seg * 136;
            int row = seg >> 1, chalf = seg & 1;
            int hp  = h0 - 1 + row;
            int xw  = w - 4;
            bool ok = ((unsigned)hp < 128u) && ((unsigned)xw < 128u);
            const float* src = xb + (size_t)(chalf * 8) * 16384 + hp * 128 + xw;
            float v[8];
            #pragma unroll
            for (int j = 0; j < 8; ++j)
                v[j] = ok ? src[(size_t)j * 16384] : 0.f;
            int slot = (chalf ^ (w >> 2)) & 1;
            unsigned* dst = (unsigned*)sx + (row * 136 + w) * 8 + slot * 4;
            #pragma unroll
            for (int j2 = 0; j2 < 4; ++j2)
                dst[j2] = pk_bf16(v[2 * j2], v[2 * j2 + 1]);
        }
    }

    // ---- weights into registers (80 VGPR), bias per lane
    bf16x8 Breg[20];
    #pragma unroll
    for (int i = 0; i < 20; ++i)
        Breg[i] = *(const bf16x8*)(bfrag + (i * 64 + lane) * 8);
    float bv[4];
    #pragma unroll
    for (int ot = 0; ot < 4; ++ot) bv[ot] = bias[ot * 16 + nlo];

    // ---- per-chunk A-read base (np=0, mt=0, rowsel=0); rest are imm offsets
    int baseA[5];
    #pragma unroll
    for (int ch = 0; ch < 5; ++ch) {
        int tap = ch * 2 + (q >> 1);
        if (tap > 8) tap = 8;             // chunk 4 upper half: pad, B=0
        int kh = tap / 3, kw = tap - 3 * kh;
        int chalf = q & 1;
        int row0  = wave * 2 + kh;
        int w0    = nlo + kw + 3;         // LDS w-index for pixel nlo
        int slot  = (chalf ^ (w0 >> 2)) & 1;
        baseA[ch] = (row0 * 136 + w0) * 16 + slot * 8;
    }
    __syncthreads();

    // ---- hot loop: 2 rows x 4 pixel-groups; per phase 5 chunks x (2 rd + 8 mfma)
    #pragma unroll
    for (int rs = 0; rs < 2; ++rs) {
        const int h = h0 + wave * 2 + rs;
        #pragma unroll
        for (int np = 0; np < 4; ++np) {
            f32x4 acc[2][4];
            #pragma unroll
            for (int ot = 0; ot < 4; ++ot) {
                f32x4 ini = { bv[ot], bv[ot], bv[ot], bv[ot] };
                acc[0][ot] = ini;
                acc[1][ot] = ini;
            }
            #pragma unroll
            for (int ch = 0; ch < 5; ++ch) {
                const short* pA = sx + baseA[ch] + rs * 2176 + np * 512;
                bf16x8 A0 = *(const bf16x8*)(pA);        // m-tile 0 (pixels +0)
                bf16x8 A1 = *(const bf16x8*)(pA + 256);  // m-tile 1 (pixels +16)
                #pragma unroll
                for (int ot = 0; ot < 4; ++ot) {
                    acc[0][ot] = __builtin_amdgcn_mfma_f32_16x16x32_bf16(A0, Breg[ch * 4 + ot], acc[0][ot], 0, 0, 0);
                    acc[1][ot] = __builtin_amdgcn_mfma_f32_16x16x32_bf16(A1, Breg[ch * 4 + ot], acc[1][ot], 0, 0, 0);
                }
            }
            // D[m = q*4+reg (pixel), n = nlo (o)] -> dwordx4 per (mt, ot).
            // R5: non-temporal (bypass L2 write-allocate; see header).
            #pragma unroll
            for (int ot = 0; ot < 4; ++ot) {
                float* dst = out + (((size_t)b * 64 + ot * 16 + nlo) * 128 + h) * 128
                           + np * 32 + q * 4;
                __builtin_nontemporal_store(acc[0][ot], (f32x4*)dst);
                __builtin_nontemporal_store(acc[1][ot], (f32x4*)(dst + 16));
            }
        }
    }
}

extern "C" void kernel_launch(void* const* d_in, const int* in_sizes, int n_in,
                              void* d_out, int out_size, void* d_ws, size_t ws_size,
                              hipStream_t stream) {
    const float* x      = (const float*)d_in[0];   // [32,16,128,128]
    const float* weight = (const float*)d_in[1];   // [64,16,15]
    const float* bias   = (const float*)d_in[2];   // [64,1]
    float* out   = (float*)d_out;                  // [32,64,128,128]
    short* bfrag = (short*)d_ws;                   // 1280*8 bf16 = 20 KB

    prep_kernel<<<5, 256, 0, stream>>>(weight, bfrag);
    dim3 grid(16, 32);                             // (h-tiles of 8 rows, b)
    conv_mfma<<<grid, 256, 0, stream>>>(x, bfrag, bias, out);
}

// Round 3
// 169.482 us; speedup vs baseline: 1.1572x; 1.1255x over previous
//
#include <hip/hip_runtime.h>
#include <hip/hip_bf16.h>

// FlippedQuanv3x3 == 3x3 conv (C=16 -> O=64, pad=1) with transformed weight
// Weff[o,c,k9] = 0.25*(sum_i w[o,c,i]*A[i,k9] + t0[k9]).
// Implicit GEMM, bf16 MFMA 16x16x32. K order = tap-major: k = tap*16 + c.
// K = 144 padded to 160 = 5 chunks. A = im2col(x) (M = pixels), B = Weff (N = o).
//
// R6 (store-writeback-locality fix): R5 proved nt stores regress (L2 was
// helping via write-combining); remaining store cost is WRITEBACK locality --
// isolated 128-B dirty lines scattered across 64 o-planes @64-KiB stride.
// New wave roles: wave = (ot-pair, row-half); each wave completes FULL
// 128-px rows for 32 o-planes, transposes through a wave-private 8-KiB LDS
// bounce (XOR-swizzled), and emits 512-B-contiguous runs per o-plane
// (2 planes / 1-KiB store instr). Zero extra barriers (wave-private bounce,
// in-wave lgkmcnt ordering). acc[2][4][2]=64 VGPR + Breg 40 (~165 total,
// no R4-style spill). A-frags re-read x2 (160 ds_read_b128/wave, +~1 us).
// Per-acc ch-chain order unchanged -> bit-identical numerics.

typedef short bf16x8 __attribute__((ext_vector_type(8)));   // 8 bf16 = 4 VGPR
typedef float f32x4 __attribute__((ext_vector_type(4)));

// ---- Pauli feature constants (verified R1-R3) ----
__device__ __forceinline__ void pauli_entry(int s, int r, int c, float& re, float& im) {
    re = 0.f; im = 0.f;
    if (s == 0)      { if (r == c) re = 1.f; }
    else if (s == 1) { if (r != c) re = 1.f; }
    else if (s == 2) { if (r == 0 && c == 1) im = -1.f; else if (r == 1 && c == 0) im = 1.f; }
    else             { if (r == c) re = (r == 0) ? 1.f : -1.f; }
}

__device__ __forceinline__ float A_entry(int i, int k) {
    int j = i + 1, sa = j >> 2, sb = j & 3;
    int r = k >> 2, c = k & 3;        // 4x4 flat embedding (M.flat[k]) — verified R1
    float ar, ai, br, bi;
    pauli_entry(sa, r >> 1, c >> 1, ar, ai);
    pauli_entry(sb, r & 1, c & 1, br, bi);
    float re1 = ar * br - ai * bi;
    pauli_entry(sa, c >> 1, r >> 1, ar, ai);
    pauli_entry(sb, c & 1, r & 1, br, bi);
    float re2 = ar * br - ai * bi;
    return 0.5f * (re1 + re2);
}

__device__ __forceinline__ short f2bf(float f) {   // RNE float->bf16 bits
    union { float f; unsigned int u; } a; a.f = f;
    unsigned int r = a.u + 0x7fffu + ((a.u >> 16) & 1u);
    return (short)(r >> 16);
}

// pack two floats -> two bf16 (RNE) in one u32 (lo = a, hi = b)
__device__ __forceinline__ unsigned pk_bf16(float a, float b) {
#if __has_builtin(__builtin_amdgcn_cvt_pk_bf16_f32)
    typedef __bf16 bf2 __attribute__((ext_vector_type(2)));
    bf2 r = __builtin_amdgcn_cvt_pk_bf16_f32(a, b);
    union { bf2 v; unsigned u; } cv; cv.v = r;
    return cv.u;
#else
    union { float f; unsigned u; } x, y; x.f = a; y.f = b;
    unsigned ra = x.u + 0x7fffu + ((x.u >> 16) & 1u);
    unsigned rb = y.u + 0x7fffu + ((y.u >> 16) & 1u);
    return (ra >> 16) | (rb & 0xffff0000u);
#endif
}

// ---- prep: Weff as MFMA B-fragments, k tap-major.
// bfrag[(chunk*4 + ot)*64 + lane][j] = Weff[o = ot*16 + (lane&15)]
//   [gk = chunk*32 + (lane>>4)*8 + j], gk -> (tap = gk>>4, c = gk&15); 0 if gk>=144.
__global__ __launch_bounds__(256) void prep_kernel(const float* __restrict__ weight,
                                                   short* __restrict__ bfrag) {
    __shared__ float Ash[135];       // Ash[i*9 + tap] = A[i, tap]
    int tid = threadIdx.x;
    if (tid < 135) Ash[tid] = A_entry(tid / 9, tid % 9);
    __syncthreads();

    int t = blockIdx.x * 256 + tid;
    if (t >= 1280) return;
    int lane  = t & 63;
    int ot    = (t >> 6) & 3;
    int chunk = t >> 8;
    int q     = lane >> 4;
    int o     = ot * 16 + (lane & 15);
    short vals[8];
    #pragma unroll
    for (int j = 0; j < 8; ++j) {
        int gk = chunk * 32 + q * 8 + j;
        float v = 0.f;
        if (gk < 144) {
            int tap = gk >> 4;         // patch index 0..8
            int c   = gk & 15;         // channel
            float acc = (tap == 0 || tap == 5) ? 1.f : 0.f;   // t0
            const float* w = weight + (o * 16 + c) * 15;
            #pragma unroll
            for (int i = 0; i < 15; ++i) acc += w[i] * Ash[i * 9 + tap];
            v = 0.25f * acc;
        }
        vals[j] = f2bf(v);
    }
    *(bf16x8*)(bfrag + t * 8) = *(bf16x8*)vals;
}

// LDS x-tile: el(row, w, c) = (row*136 + w)*16 + slot*8 + (c&7),
// slot = (c>>3) ^ ((w>>2)&1). row in [0,10) = x rows h0-1..h0+8; w in [0,136)
// = x w -4..131. Row stride 4352 B == 0 mod 32 banks; hot-loop b128 reads
// <=2-way conflicted (free, m136).
__global__ __launch_bounds__(256) void conv_mfma(const float* __restrict__ x,
                                                 const short* __restrict__ bfrag,
                                                 const float* __restrict__ bias,
                                                 float* __restrict__ out) {
    __shared__ short sx[10 * 136 * 16];            // 43520 B
    __shared__ __align__(16) float obuf[8192];     // 32768 B: 8 KiB per wave

    const int tid  = threadIdx.x;
    const int h0   = blockIdx.x * 8;
    const int b    = blockIdx.y;
    const int lane = tid & 63;
    const int wave = tid >> 6;
    const int q    = lane >> 4;
    const int nlo  = lane & 15;
    const int otp  = wave >> 1;       // ot-pair: owns o-groups {otp*2, otp*2+1}
    const int hh   = wave & 1;        // row-half: owns rows hh*4 .. hh*4+3

    // ---- stage x -> bf16 c-fastest LDS tile. 2720 positions = (row,chalf,w).
    const float* xb = x + (size_t)b * 16 * 128 * 128;
    #pragma unroll
    for (int it = 0; it < 11; ++it) {
        int pos = tid + it * 256;
        if (pos < 2720) {
            int seg = pos / 136;           // row*2 + chalf
            int w   = pos - seg * 136;
            int row = seg >> 1, chalf = seg & 1;
            int hp  = h0 - 1 + row;
            int xw  = w - 4;
            bool ok = ((unsigned)hp < 128u) && ((unsigned)xw < 128u);
            const float* src = xb + (size_t)(chalf * 8) * 16384 + hp * 128 + xw;
            float v[8];
            #pragma unroll
            for (int j = 0; j < 8; ++j)
                v[j] = ok ? src[(size_t)j * 16384] : 0.f;
            int slot = (chalf ^ (w >> 2)) & 1;
            unsigned* dst = (unsigned*)sx + (row * 136 + w) * 8 + slot * 4;
            #pragma unroll
            for (int j2 = 0; j2 < 4; ++j2)
                dst[j2] = pk_bf16(v[2 * j2], v[2 * j2 + 1]);
        }
    }

    // ---- weights for this wave's 2 o-groups (40 VGPR), bias per lane
    bf16x8 Breg[10];
    #pragma unroll
    for (int ch = 0; ch < 5; ++ch)
        #pragma unroll
        for (int j = 0; j < 2; ++j)
            Breg[ch * 2 + j] = *(const bf16x8*)(bfrag + ((ch * 4 + otp * 2 + j) * 64 + lane) * 8);
    float bv[2];
    #pragma unroll
    for (int j = 0; j < 2; ++j) bv[j] = bias[(otp * 2 + j) * 16 + nlo];

    // ---- per-chunk A-read base; r (row 0..3) and np are imm offsets
    int baseA[5];
    #pragma unroll
    for (int ch = 0; ch < 5; ++ch) {
        int tap = ch * 2 + (q >> 1);
        if (tap > 8) tap = 8;             // chunk 4 upper half: pad, B=0
        int kh = tap / 3, kw = tap - 3 * kh;
        int chalf = q & 1;
        int row0  = hh * 4 + kh;
        int w0    = nlo + kw + 3;         // LDS w-index for pixel nlo
        int slot  = (chalf ^ (w0 >> 2)) & 1;
        baseA[ch] = (row0 * 136 + w0) * 16 + slot * 8;
    }
    __syncthreads();

    // ---- hot loop: 4 rows; per row accumulate 2 o-groups x full 128 px,
    // then bounce-transpose and store 512-B-contiguous runs per o-plane.
    #pragma unroll
    for (int r = 0; r < 4; ++r) {
        const int h = h0 + hh * 4 + r;
        f32x4 acc[2][4][2];               // [ot-in-pair][np][mt] = 64 VGPR
        #pragma unroll
        for (int j = 0; j < 2; ++j)
            #pragma unroll
            for (int np = 0; np < 4; ++np) {
                f32x4 ini = { bv[j], bv[j], bv[j], bv[j] };
                acc[j][np][0] = ini;
                acc[j][np][1] = ini;
            }
        #pragma unroll
        for (int np = 0; np < 4; ++np) {
            #pragma unroll
            for (int ch = 0; ch < 5; ++ch) {
                const short* pA = sx + baseA[ch] + r * 2176 + np * 512;
                bf16x8 A0 = *(const bf16x8*)(pA);        // pixels np*32+0..15
                bf16x8 A1 = *(const bf16x8*)(pA + 256);  // pixels np*32+16..31
                #pragma unroll
                for (int j = 0; j < 2; ++j) {
                    acc[j][np][0] = __builtin_amdgcn_mfma_f32_16x16x32_bf16(A0, Breg[ch * 2 + j], acc[j][np][0], 0, 0, 0);
                    acc[j][np][1] = __builtin_amdgcn_mfma_f32_16x16x32_bf16(A1, Breg[ch * 2 + j], acc[j][np][1], 0, 0, 0);
                }
            }
        }
        // ---- epilogue per o-group: wave-private bounce (swizzled) then
        // 512-B-contiguous stores (2 o-planes per 1-KiB instruction).
        // D frag: lane holds px = np*32+mt*16+q*4..+3 for o_loc = nlo.
        #pragma unroll
        for (int j = 0; j < 2; ++j) {
            #pragma unroll
            for (int np = 0; np < 4; ++np)
                #pragma unroll
                for (int mt = 0; mt < 2; ++mt) {
                    int px  = np * 32 + mt * 16 + q * 4;
                    int idx = wave * 2048 + nlo * 128 + (px ^ ((nlo & 7) << 2));
                    *(f32x4*)(obuf + idx) = acc[j][np][mt];
                }
            // in-wave lgkmcnt orders write->read (same wave, aliasing LDS)
            float* outp = out + (((size_t)b * 64 + (otp * 2 + j) * 16) * 128 + h) * 128;
            #pragma unroll
            for (int i = 0; i < 8; ++i) {
                int o   = 2 * i + (lane >> 5);     // o within group, 0..15
                int px  = (lane & 31) * 4;
                int ridx = wave * 2048 + o * 128 + (px ^ ((o & 7) << 2));
                f32x4 v = *(const f32x4*)(obuf + ridx);
                *(f32x4*)(outp + (size_t)o * 16384 + px) = v;
            }
        }
    }
}

extern "C" void kernel_launch(void* const* d_in, const int* in_sizes, int n_in,
                              void* d_out, int out_size, void* d_ws, size_t ws_size,
                              hipStream_t stream) {
    const float* x      = (const float*)d_in[0];   // [32,16,128,128]
    const float* weight = (const float*)d_in[1];   // [64,16,15]
    const float* bias   = (const float*)d_in[2];   // [64,1]
    float* out   = (float*)d_out;                  // [32,64,128,128]
    short* bfrag = (short*)d_ws;                   // 1280*8 bf16 = 20 KB

    prep_kernel<<<5, 256, 0, stream>>>(weight, bfrag);
    dim3 grid(16, 32);                             // (h-tiles of 8 rows, b)
    conv_mfma<<<grid, 256, 0, stream>>>(x, bfrag, bias, out);
}

// Round 4
// 166.863 us; speedup vs baseline: 1.1754x; 1.0157x over previous
//
#include <hip/hip_runtime.h>
#include <hip/hip_bf16.h>

// FlippedQuanv3x3 == 3x3 conv (C=16 -> O=64, pad=1) with transformed weight
// Weff[o,c,k9] = 0.25*(sum_i w[o,c,i]*A[i,k9] + t0[k9]).
// Implicit GEMM, bf16 MFMA 16x16x32. K order = tap-major: k = tap*16 + c.
// K = 144 padded to 160 = 5 chunks. A = im2col(x) (M = pixels), B = Weff (N = o).
//
// R7 (occupancy/convoy fix): R5/R6 falsified store-pattern theories (nt -21us,
// 512B-run bounce +-0). Remaining gap theory: grid 512 = 2 blocks/CU = 2
// waves/SIMD -> stage/compute/store convoy with no cross-block overlap and
// weak latency hiding. Now: 4-row tiles, grid 32x32=1024 = 4 blocks/CU all
// co-resident (16 waves/CU). VGPR diet for 4 waves/SIMD (<=128): R6's
// proven-neutral Breg split (wave owns 2 o-groups, 40 VGPR) + per-np acc
// (16 VGPR), __launch_bounds__(256,4). LDS 26.1 KB x4 = 104 KB. Epilogue =
// R0's proven direct dwordx4 stores. MFMA ch-chain order unchanged ->
// bit-identical numerics. Cost: halo factor 6/4 (reads 40->48 MB, +1.6us).

typedef short bf16x8 __attribute__((ext_vector_type(8)));   // 8 bf16 = 4 VGPR
typedef float f32x4 __attribute__((ext_vector_type(4)));

// ---- Pauli feature constants (verified R1-R3) ----
__device__ __forceinline__ void pauli_entry(int s, int r, int c, float& re, float& im) {
    re = 0.f; im = 0.f;
    if (s == 0)      { if (r == c) re = 1.f; }
    else if (s == 1) { if (r != c) re = 1.f; }
    else if (s == 2) { if (r == 0 && c == 1) im = -1.f; else if (r == 1 && c == 0) im = 1.f; }
    else             { if (r == c) re = (r == 0) ? 1.f : -1.f; }
}

__device__ __forceinline__ float A_entry(int i, int k) {
    int j = i + 1, sa = j >> 2, sb = j & 3;
    int r = k >> 2, c = k & 3;        // 4x4 flat embedding (M.flat[k]) — verified R1
    float ar, ai, br, bi;
    pauli_entry(sa, r >> 1, c >> 1, ar, ai);
    pauli_entry(sb, r & 1, c & 1, br, bi);
    float re1 = ar * br - ai * bi;
    pauli_entry(sa, c >> 1, r >> 1, ar, ai);
    pauli_entry(sb, c & 1, r & 1, br, bi);
    float re2 = ar * br - ai * bi;
    return 0.5f * (re1 + re2);
}

__device__ __forceinline__ short f2bf(float f) {   // RNE float->bf16 bits
    union { float f; unsigned int u; } a; a.f = f;
    unsigned int r = a.u + 0x7fffu + ((a.u >> 16) & 1u);
    return (short)(r >> 16);
}

// pack two floats -> two bf16 (RNE) in one u32 (lo = a, hi = b)
__device__ __forceinline__ unsigned pk_bf16(float a, float b) {
#if __has_builtin(__builtin_amdgcn_cvt_pk_bf16_f32)
    typedef __bf16 bf2 __attribute__((ext_vector_type(2)));
    bf2 r = __builtin_amdgcn_cvt_pk_bf16_f32(a, b);
    union { bf2 v; unsigned u; } cv; cv.v = r;
    return cv.u;
#else
    union { float f; unsigned u; } x, y; x.f = a; y.f = b;
    unsigned ra = x.u + 0x7fffu + ((x.u >> 16) & 1u);
    unsigned rb = y.u + 0x7fffu + ((y.u >> 16) & 1u);
    return (ra >> 16) | (rb & 0xffff0000u);
#endif
}

// ---- prep: Weff as MFMA B-fragments, k tap-major.
// bfrag[(chunk*4 + ot)*64 + lane][j] = Weff[o = ot*16 + (lane&15)]
//   [gk = chunk*32 + (lane>>4)*8 + j], gk -> (tap = gk>>4, c = gk&15); 0 if gk>=144.
__global__ __launch_bounds__(256) void prep_kernel(const float* __restrict__ weight,
                                                   short* __restrict__ bfrag) {
    __shared__ float Ash[135];       // Ash[i*9 + tap] = A[i, tap]
    int tid = threadIdx.x;
    if (tid < 135) Ash[tid] = A_entry(tid / 9, tid % 9);
    __syncthreads();

    int t = blockIdx.x * 256 + tid;
    if (t >= 1280) return;
    int lane  = t & 63;
    int ot    = (t >> 6) & 3;
    int chunk = t >> 8;
    int q     = lane >> 4;
    int o     = ot * 16 + (lane & 15);
    short vals[8];
    #pragma unroll
    for (int j = 0; j < 8; ++j) {
        int gk = chunk * 32 + q * 8 + j;
        float v = 0.f;
        if (gk < 144) {
            int tap = gk >> 4;         // patch index 0..8
            int c   = gk & 15;         // channel
            float acc = (tap == 0 || tap == 5) ? 1.f : 0.f;   // t0
            const float* w = weight + (o * 16 + c) * 15;
            #pragma unroll
            for (int i = 0; i < 15; ++i) acc += w[i] * Ash[i * 9 + tap];
            v = 0.25f * acc;
        }
        vals[j] = f2bf(v);
    }
    *(bf16x8*)(bfrag + t * 8) = *(bf16x8*)vals;
}

// LDS x-tile: el(row, w, c) = (row*136 + w)*16 + slot*8 + (c&7),
// slot = (c>>3) ^ ((w>>2)&1). row in [0,6) = x rows h0-1..h0+4; w in [0,136)
// = x w -4..131. Row stride 4352 B == 0 mod 32 banks; hot-loop b128 reads
// <=2-way conflicted (free, m136).
__global__ __launch_bounds__(256, 4) void conv_mfma(const float* __restrict__ x,
                                                    const short* __restrict__ bfrag,
                                                    const float* __restrict__ bias,
                                                    float* __restrict__ out) {
    __shared__ short sx[6 * 136 * 16];   // 26112 B -> 4 blocks/CU

    const int tid  = threadIdx.x;
    const int h0   = blockIdx.x * 4;
    const int b    = blockIdx.y;
    const int lane = tid & 63;
    const int wave = tid >> 6;
    const int q    = lane >> 4;
    const int nlo  = lane & 15;
    const int otp  = wave >> 1;       // ot-pair: owns o-groups {otp*2, otp*2+1}
    const int rh   = wave & 1;        // row-half: owns output rows rh*2, rh*2+1

    // ---- stage x -> bf16 c-fastest LDS tile. 1632 positions = (row,chalf,w).
    const float* xb = x + (size_t)b * 16 * 128 * 128;
    #pragma unroll
    for (int it = 0; it < 7; ++it) {
        int pos = tid + it * 256;
        if (pos < 1632) {
            int seg = pos / 136;           // row*2 + chalf
            int w   = pos - seg * 136;
            int row = seg >> 1, chalf = seg & 1;
            int hp  = h0 - 1 + row;
            int xw  = w - 4;
            bool ok = ((unsigned)hp < 128u) && ((unsigned)xw < 128u);
            const float* src = xb + (size_t)(chalf * 8) * 16384 + hp * 128 + xw;
            float v[8];
            #pragma unroll
            for (int j = 0; j < 8; ++j)
                v[j] = ok ? src[(size_t)j * 16384] : 0.f;
            int slot = (chalf ^ (w >> 2)) & 1;
            unsigned* dst = (unsigned*)sx + (row * 136 + w) * 8 + slot * 4;
            #pragma unroll
            for (int j2 = 0; j2 < 4; ++j2)
                dst[j2] = pk_bf16(v[2 * j2], v[2 * j2 + 1]);
        }
    }

    // ---- weights for this wave's 2 o-groups (40 VGPR), bias per lane
    bf16x8 Breg[10];
    #pragma unroll
    for (int ch = 0; ch < 5; ++ch)
        #pragma unroll
        for (int j = 0; j < 2; ++j)
            Breg[ch * 2 + j] = *(const bf16x8*)(bfrag + ((ch * 4 + otp * 2 + j) * 64 + lane) * 8);
    float bv[2];
    #pragma unroll
    for (int j = 0; j < 2; ++j) bv[j] = bias[(otp * 2 + j) * 16 + nlo];

    // ---- per-chunk A-read base; r (row 0..1) and np are imm offsets
    int baseA[5];
    #pragma unroll
    for (int ch = 0; ch < 5; ++ch) {
        int tap = ch * 2 + (q >> 1);
        if (tap > 8) tap = 8;             // chunk 4 upper half: pad, B=0
        int kh = tap / 3, kw = tap - 3 * kh;
        int chalf = q & 1;
        int row0  = rh * 2 + kh;
        int w0    = nlo + kw + 3;         // LDS w-index for pixel nlo
        int slot  = (chalf ^ (w0 >> 2)) & 1;
        baseA[ch] = (row0 * 136 + w0) * 16 + slot * 8;
    }
    __syncthreads();

    // ---- hot loop: 2 rows x 4 pixel-groups; per np: 5 chunks x (2 rd + 4 mfma),
    // then direct dwordx4 stores (R0-proven epilogue).
    #pragma unroll
    for (int r = 0; r < 2; ++r) {
        const int h = h0 + rh * 2 + r;
        #pragma unroll
        for (int np = 0; np < 4; ++np) {
            f32x4 acc[2][2];              // [ot-in-pair][mt] = 16 VGPR
            #pragma unroll
            for (int j = 0; j < 2; ++j) {
                f32x4 ini = { bv[j], bv[j], bv[j], bv[j] };
                acc[j][0] = ini;
                acc[j][1] = ini;
            }
            #pragma unroll
            for (int ch = 0; ch < 5; ++ch) {
                const short* pA = sx + baseA[ch] + r * 2176 + np * 512;
                bf16x8 A0 = *(const bf16x8*)(pA);        // pixels np*32+0..15
                bf16x8 A1 = *(const bf16x8*)(pA + 256);  // pixels np*32+16..31
                #pragma unroll
                for (int j = 0; j < 2; ++j) {
                    acc[j][0] = __builtin_amdgcn_mfma_f32_16x16x32_bf16(A0, Breg[ch * 2 + j], acc[j][0], 0, 0, 0);
                    acc[j][1] = __builtin_amdgcn_mfma_f32_16x16x32_bf16(A1, Breg[ch * 2 + j], acc[j][1], 0, 0, 0);
                }
            }
            // D[m = q*4+reg (pixel), n = nlo (o)] -> dwordx4 per (mt, j)
            #pragma unroll
            for (int j = 0; j < 2; ++j) {
                float* dst = out + (((size_t)b * 64 + (otp * 2 + j) * 16 + nlo) * 128 + h) * 128
                           + np * 32 + q * 4;
                *(f32x4*)dst        = acc[j][0];
                *(f32x4*)(dst + 16) = acc[j][1];
            }
        }
    }
}

extern "C" void kernel_launch(void* const* d_in, const int* in_sizes, int n_in,
                              void* d_out, int out_size, void* d_ws, size_t ws_size,
                              hipStream_t stream) {
    const float* x      = (const float*)d_in[0];   // [32,16,128,128]
    const float* weight = (const float*)d_in[1];   // [64,16,15]
    const float* bias   = (const float*)d_in[2];   // [64,1]
    float* out   = (float*)d_out;                  // [32,64,128,128]
    short* bfrag = (short*)d_ws;                   // 1280*8 bf16 = 20 KB

    prep_kernel<<<5, 256, 0, stream>>>(weight, bfrag);
    dim3 grid(32, 32);                             // (h-tiles of 4 rows, b) = 4 blocks/CU
    conv_mfma<<<grid, 256, 0, stream>>>(x, bfrag, bias, out);
}